// Round 1
// baseline (115.979 us; speedup 1.0000x reference)
//
#include <hip/hip_runtime.h>

#define BATCH   4096
#define IN_DIM  512
#define OUT_DIM 32
// ARITY = 4, 2^ARITY = 16 param rows per channel

__global__ __launch_bounds__(256) void simplex_interp_kernel(
    const float* __restrict__ X,       // [BATCH, IN_DIM, 4]
    const float* __restrict__ params,  // [IN_DIM, 16, OUT_DIM]
    float* __restrict__ out)           // [BATCH, IN_DIM, OUT_DIM]
{
    const int tid  = blockIdx.x * blockDim.x + threadIdx.x;
    const int pair = tid >> 3;          // which (b,g) pair
    const int sub  = tid & 7;           // which float4 of the 32 outputs

    // grid sized exactly: pair < BATCH*IN_DIM always
    const int g = pair & (IN_DIM - 1);

    // ---- load the 4 inputs for this pair (16B, 8-way broadcast per group) ----
    const float4 xv = *reinterpret_cast<const float4*>(X + (size_t)pair * 4);

    float v0 = xv.x, v1 = xv.y, v2 = xv.z, v3 = xv.w;
    int   i0 = 0,    i1 = 1,    i2 = 2,    i3 = 3;

    // ---- 5-comparator sorting network, ascending (branchless) ----
    #define CSWAP(va, vb, ia, ib)                        \
    {                                                    \
        bool lt = (vb) < (va);                           \
        float tv = (va); (va) = lt ? (vb) : (va); (vb) = lt ? tv : (vb); \
        int   ti = (ia); (ia) = lt ? (ib) : (ia); (ib) = lt ? ti : (ib); \
    }
    CSWAP(v0, v1, i0, i1)
    CSWAP(v2, v3, i2, i3)
    CSWAP(v0, v2, i0, i2)
    CSWAP(v1, v3, i1, i3)
    CSWAP(v1, v2, i1, i2)
    #undef CSWAP

    // ---- coefficients from sorted gaps ----
    const float c0 = v0;
    const float c1 = v1 - v0;
    const float c2 = v2 - v1;
    const float c3 = v3 - v2;

    // ---- reverse-cumsum bitmask indices ----
    const int idx3 = (1 << i3);
    const int idx2 = (1 << i2) + idx3;
    const int idx1 = (1 << i1) + idx2;
    const int idx0 = 15;   // all bits set

    // ---- gather 4 param rows (this lane's float4 slice) and accumulate ----
    const float* pg = params + ((size_t)g * 16) * OUT_DIM + sub * 4;
    const float4 p0 = *reinterpret_cast<const float4*>(pg + idx0 * OUT_DIM);
    const float4 p1 = *reinterpret_cast<const float4*>(pg + idx1 * OUT_DIM);
    const float4 p2 = *reinterpret_cast<const float4*>(pg + idx2 * OUT_DIM);
    const float4 p3 = *reinterpret_cast<const float4*>(pg + idx3 * OUT_DIM);

    float4 acc;
    acc.x = c0 * p0.x + c1 * p1.x + c2 * p2.x + c3 * p3.x;
    acc.y = c0 * p0.y + c1 * p1.y + c2 * p2.y + c3 * p3.y;
    acc.z = c0 * p0.z + c1 * p1.z + c2 * p2.z + c3 * p3.z;
    acc.w = c0 * p0.w + c1 * p1.w + c2 * p2.w + c3 * p3.w;

    *reinterpret_cast<float4*>(out + (size_t)pair * OUT_DIM + sub * 4) = acc;
}

extern "C" void kernel_launch(void* const* d_in, const int* in_sizes, int n_in,
                              void* d_out, int out_size, void* d_ws, size_t ws_size,
                              hipStream_t stream) {
    const float* X      = (const float*)d_in[0];
    const float* params = (const float*)d_in[1];
    float*       out    = (float*)d_out;

    // total threads = BATCH * IN_DIM * (OUT_DIM/4) = 4096*512*8 = 16,777,216
    const long long total   = (long long)BATCH * IN_DIM * (OUT_DIM / 4);
    const int       block   = 256;
    const int       nblocks = (int)(total / block);   // 65536, exact

    simplex_interp_kernel<<<nblocks, block, 0, stream>>>(X, params, out);
}

// Round 2
// 107.983 us; speedup vs baseline: 1.0740x; 1.0740x over previous
//
#include <hip/hip_runtime.h>

#define BATCH   4096
#define IN_DIM  512
#define OUT_DIM 32
// ARITY = 4, 2^ARITY = 16 param rows per channel

typedef float f32x4 __attribute__((ext_vector_type(4)));

__global__ __launch_bounds__(256) void simplex_interp_kernel(
    const float* __restrict__ X,       // [BATCH, IN_DIM, 4]
    const float* __restrict__ params,  // [IN_DIM, 16, OUT_DIM]
    float* __restrict__ out)           // [BATCH, IN_DIM, OUT_DIM]
{
    const int tid  = blockIdx.x * blockDim.x + threadIdx.x;
    const int pair = tid >> 3;          // which (b,g) pair
    const int sub  = tid & 7;           // which float4 of the 32 outputs

    const int g = pair & (IN_DIM - 1);

    // ---- X is streaming (each line consumed entirely by this one wave):
    // non-temporal load keeps it out of L2.
    const f32x4 xv = __builtin_nontemporal_load(
        reinterpret_cast<const f32x4*>(X + (size_t)pair * 4));

    float v0 = xv.x, v1 = xv.y, v2 = xv.z, v3 = xv.w;
    int   i0 = 0,    i1 = 1,    i2 = 2,    i3 = 3;

    // ---- 5-comparator sorting network, ascending (branchless) ----
    #define CSWAP(va, vb, ia, ib)                        \
    {                                                    \
        bool lt = (vb) < (va);                           \
        float tv = (va); (va) = lt ? (vb) : (va); (vb) = lt ? tv : (vb); \
        int   ti = (ia); (ia) = lt ? (ib) : (ia); (ib) = lt ? ti : (ib); \
    }
    CSWAP(v0, v1, i0, i1)
    CSWAP(v2, v3, i2, i3)
    CSWAP(v0, v2, i0, i2)
    CSWAP(v1, v3, i1, i3)
    CSWAP(v1, v2, i1, i2)
    #undef CSWAP

    // ---- coefficients from sorted gaps ----
    const float c0 = v0;
    const float c1 = v1 - v0;
    const float c2 = v2 - v1;
    const float c3 = v3 - v2;

    // ---- reverse-cumsum bitmask indices ----
    const int idx3 = (1 << i3);
    const int idx2 = (1 << i2) + idx3;
    const int idx1 = (1 << i1) + idx2;
    const int idx0 = 15;   // all bits set

    // ---- gather 4 param rows (this lane's float4 slice); params stay
    // L2-resident because out/X no longer pollute it.
    const float* pg = params + ((size_t)g * 16) * OUT_DIM + sub * 4;
    const f32x4 p0 = *reinterpret_cast<const f32x4*>(pg + idx0 * OUT_DIM);
    const f32x4 p1 = *reinterpret_cast<const f32x4*>(pg + idx1 * OUT_DIM);
    const f32x4 p2 = *reinterpret_cast<const f32x4*>(pg + idx2 * OUT_DIM);
    const f32x4 p3 = *reinterpret_cast<const f32x4*>(pg + idx3 * OUT_DIM);

    const f32x4 acc = c0 * p0 + c1 * p1 + c2 * p2 + c3 * p3;

    // ---- streaming store: bypass L2 (no reuse, pure write-out) ----
    __builtin_nontemporal_store(
        acc, reinterpret_cast<f32x4*>(out + (size_t)pair * OUT_DIM + sub * 4));
}

extern "C" void kernel_launch(void* const* d_in, const int* in_sizes, int n_in,
                              void* d_out, int out_size, void* d_ws, size_t ws_size,
                              hipStream_t stream) {
    const float* X      = (const float*)d_in[0];
    const float* params = (const float*)d_in[1];
    float*       out    = (float*)d_out;

    const long long total   = (long long)BATCH * IN_DIM * (OUT_DIM / 4);
    const int       block   = 256;
    const int       nblocks = (int)(total / block);   // 65536, exact

    simplex_interp_kernel<<<nblocks, block, 0, stream>>>(X, params, out);
}

// Round 3
// 106.476 us; speedup vs baseline: 1.0892x; 1.0142x over previous
//
#include <hip/hip_runtime.h>

#define BATCH   4096
#define IN_DIM  512
#define OUT_DIM 32
#define KP      4   // pairs (phases) per thread

typedef float f32x4 __attribute__((ext_vector_type(4)));

// sort 4 values + build gap coefficients and the 3 variable gather offsets
__device__ __forceinline__ void prep(const f32x4 xv, f32x4& cf,
                                     int& o1, int& o2, int& o3)
{
    float v0 = xv.x, v1 = xv.y, v2 = xv.z, v3 = xv.w;
    int   i0 = 0,    i1 = 1,    i2 = 2,    i3 = 3;
#define CSWAP(va, vb, ia, ib)                                            \
    {                                                                    \
        bool lt = (vb) < (va);                                           \
        float tv = (va); (va) = lt ? (vb) : (va); (vb) = lt ? tv : (vb); \
        int   ti = (ia); (ia) = lt ? (ib) : (ia); (ib) = lt ? ti : (ib); \
    }
    CSWAP(v0, v1, i0, i1)
    CSWAP(v2, v3, i2, i3)
    CSWAP(v0, v2, i0, i2)
    CSWAP(v1, v3, i1, i3)
    CSWAP(v1, v2, i1, i2)
#undef CSWAP
    cf.x = v0;
    cf.y = v1 - v0;
    cf.z = v2 - v1;
    cf.w = v3 - v2;
    const int idx3 = (1 << i3);
    const int idx2 = idx3 + (1 << i2);
    const int idx1 = idx2 + (1 << i1);
    o1 = idx1 * OUT_DIM;
    o2 = idx2 * OUT_DIM;
    o3 = idx3 * OUT_DIM;
    // idx0 == 15 always -> handled by the shared p15 row outside
}

__global__ __launch_bounds__(256) void simplex_interp_kernel(
    const float* __restrict__ X,       // [BATCH, IN_DIM, 4]
    const float* __restrict__ params,  // [IN_DIM, 16, OUT_DIM]
    float* __restrict__ out)           // [BATCH, IN_DIM, OUT_DIM]
{
    const int tid    = blockIdx.x * blockDim.x + threadIdx.x;
    const int sub    = tid & 7;                  // float4 slice of the 32 outputs
    const int p0     = tid >> 3;                 // base pair for phase 0
    const int STRIDE = (BATCH / KP) * IN_DIM;    // 524288; multiple of IN_DIM

    // channel is identical across the 4 phases (STRIDE % IN_DIM == 0)
    const int g = p0 & (IN_DIM - 1);
    const float* pg = params + (size_t)g * (16 * OUT_DIM) + sub * 4;

    // ---- phase X loads: 4 independent non-temporal loads, issued together ----
    const f32x4 xv0 = __builtin_nontemporal_load((const f32x4*)(X + (size_t)(p0 + 0 * STRIDE) * 4));
    const f32x4 xv1 = __builtin_nontemporal_load((const f32x4*)(X + (size_t)(p0 + 1 * STRIDE) * 4));
    const f32x4 xv2 = __builtin_nontemporal_load((const f32x4*)(X + (size_t)(p0 + 2 * STRIDE) * 4));
    const f32x4 xv3 = __builtin_nontemporal_load((const f32x4*)(X + (size_t)(p0 + 3 * STRIDE) * 4));

    // ---- shared hot row: idx0 == 15 for every pair ----
    const f32x4 p15 = *reinterpret_cast<const f32x4*>(pg + 15 * OUT_DIM);

    // ---- sorts (VALU, overlaps with remaining load latency) ----
    f32x4 cf0, cf1, cf2, cf3;
    int a1, a2, a3, b1, b2, b3, c1, c2, c3, d1, d2, d3;
    prep(xv0, cf0, a1, a2, a3);
    prep(xv1, cf1, b1, b2, b3);
    prep(xv2, cf2, c1, c2, c3);
    prep(xv3, cf3, d1, d2, d3);

    // ---- 12 independent gathers (L2-resident params) ----
    const f32x4 q01 = *reinterpret_cast<const f32x4*>(pg + a1);
    const f32x4 q02 = *reinterpret_cast<const f32x4*>(pg + a2);
    const f32x4 q03 = *reinterpret_cast<const f32x4*>(pg + a3);
    const f32x4 q11 = *reinterpret_cast<const f32x4*>(pg + b1);
    const f32x4 q12 = *reinterpret_cast<const f32x4*>(pg + b2);
    const f32x4 q13 = *reinterpret_cast<const f32x4*>(pg + b3);
    const f32x4 q21 = *reinterpret_cast<const f32x4*>(pg + c1);
    const f32x4 q22 = *reinterpret_cast<const f32x4*>(pg + c2);
    const f32x4 q23 = *reinterpret_cast<const f32x4*>(pg + c3);
    const f32x4 q31 = *reinterpret_cast<const f32x4*>(pg + d1);
    const f32x4 q32 = *reinterpret_cast<const f32x4*>(pg + d2);
    const f32x4 q33 = *reinterpret_cast<const f32x4*>(pg + d3);

    // ---- accumulate + streaming stores ----
    const size_t obase = (size_t)sub * 4;
    {
        const f32x4 acc = cf0.x * p15 + cf0.y * q01 + cf0.z * q02 + cf0.w * q03;
        __builtin_nontemporal_store(acc,
            (f32x4*)(out + (size_t)(p0 + 0 * STRIDE) * OUT_DIM + obase));
    }
    {
        const f32x4 acc = cf1.x * p15 + cf1.y * q11 + cf1.z * q12 + cf1.w * q13;
        __builtin_nontemporal_store(acc,
            (f32x4*)(out + (size_t)(p0 + 1 * STRIDE) * OUT_DIM + obase));
    }
    {
        const f32x4 acc = cf2.x * p15 + cf2.y * q21 + cf2.z * q22 + cf2.w * q23;
        __builtin_nontemporal_store(acc,
            (f32x4*)(out + (size_t)(p0 + 2 * STRIDE) * OUT_DIM + obase));
    }
    {
        const f32x4 acc = cf3.x * p15 + cf3.y * q31 + cf3.z * q32 + cf3.w * q33;
        __builtin_nontemporal_store(acc,
            (f32x4*)(out + (size_t)(p0 + 3 * STRIDE) * OUT_DIM + obase));
    }
}

extern "C" void kernel_launch(void* const* d_in, const int* in_sizes, int n_in,
                              void* d_out, int out_size, void* d_ws, size_t ws_size,
                              hipStream_t stream) {
    const float* X      = (const float*)d_in[0];
    const float* params = (const float*)d_in[1];
    float*       out    = (float*)d_out;

    // threads = (BATCH*IN_DIM/KP) pairs-per-phase * 8 lanes = 4,194,304
    const long long total   = ((long long)BATCH * IN_DIM / KP) * (OUT_DIM / 4);
    const int       block   = 256;
    const int       nblocks = (int)(total / block);   // 16384, exact

    simplex_interp_kernel<<<nblocks, block, 0, stream>>>(X, params, out);
}

// Round 4
// 81.016 us; speedup vs baseline: 1.4316x; 1.3143x over previous
//
#include <hip/hip_runtime.h>

#define BATCH   4096
#define IN_DIM  512
#define OUT_DIM 32
#define CH      16   // channels per block
#define NB      64   // batches per block
#define NITER   32   // NB/2 : 256 threads = 2 batches x 16 ch x 8 subs

typedef float f32x4 __attribute__((ext_vector_type(4)));

__global__ __launch_bounds__(256) void simplex_interp_lds(
    const float* __restrict__ X,       // [BATCH, IN_DIM, 4]
    const float* __restrict__ params,  // [IN_DIM, 16, OUT_DIM]
    float* __restrict__ out)           // [BATCH, IN_DIM, OUT_DIM]
{
    __shared__ float lds[CH * 16 * OUT_DIM];   // 16 ch * 16 rows * 32 f = 32 KB

    const int tid = threadIdx.x;
    const int cg  = blockIdx.x & 31;           // channel group (512/CH = 32)
    const int bg  = blockIdx.x >> 5;           // batch group (0..63)
    const int b0  = bg * NB;

    // ---- stage params for channels [cg*16, cg*16+16) : 32 KB contiguous ----
    {
        const float* src = params + (size_t)cg * (CH * 16 * OUT_DIM);
        #pragma unroll
        for (int k = 0; k < 8; ++k) {
            const int off = (k * 256 + tid) * 4;          // float offset
            *reinterpret_cast<f32x4*>(&lds[off]) =
                *reinterpret_cast<const f32x4*>(src + off);
        }
    }
    __syncthreads();

    const int half = tid >> 7;          // which of the 2 batches this iteration
    const int c    = (tid >> 3) & 15;   // local channel
    const int sub  = tid & 7;           // float4 slice of the 32 outputs
    const int g    = cg * CH + c;

    const float* ldsc = &lds[c * (16 * OUT_DIM) + sub * 4];
    const f32x4  p15  = *reinterpret_cast<const f32x4*>(ldsc + 15 * OUT_DIM);

    int b = b0 + half;
    f32x4 xv = __builtin_nontemporal_load(
        reinterpret_cast<const f32x4*>(X + ((size_t)b * IN_DIM + g) * 4));

    #pragma unroll 4
    for (int i = 0; i < NITER; ++i) {
        const int bcur = b;
        b += 2;
        f32x4 xn = xv;
        if (i + 1 < NITER)       // wave-uniform condition
            xn = __builtin_nontemporal_load(
                reinterpret_cast<const f32x4*>(X + ((size_t)b * IN_DIM + g) * 4));

        // ---- 5-comparator sort network, ascending (branchless) ----
        float v0 = xv.x, v1 = xv.y, v2 = xv.z, v3 = xv.w;
        int   i0 = 0,    i1 = 1,    i2 = 2,    i3 = 3;
#define CSWAP(va, vb, ia, ib)                                            \
        {                                                                \
            bool lt = (vb) < (va);                                       \
            float tv = (va); (va) = lt ? (vb) : (va); (vb) = lt ? tv : (vb); \
            int   ti = (ia); (ia) = lt ? (ib) : (ia); (ib) = lt ? ti : (ib); \
        }
        CSWAP(v0, v1, i0, i1)
        CSWAP(v2, v3, i2, i3)
        CSWAP(v0, v2, i0, i2)
        CSWAP(v1, v3, i1, i3)
        CSWAP(v1, v2, i1, i2)
#undef CSWAP

        const float c0 = v0;
        const float c1 = v1 - v0;
        const float c2 = v2 - v1;
        const float c3 = v3 - v2;

        const int idx3 = (1 << i3);
        const int idx2 = idx3 + (1 << i2);
        const int idx1 = idx2 + (1 << i1);

        // ---- LDS gathers: each 8-lane group reads a full 128-B row -> bank-balanced ----
        const f32x4 q1 = *reinterpret_cast<const f32x4*>(ldsc + idx1 * OUT_DIM);
        const f32x4 q2 = *reinterpret_cast<const f32x4*>(ldsc + idx2 * OUT_DIM);
        const f32x4 q3 = *reinterpret_cast<const f32x4*>(ldsc + idx3 * OUT_DIM);

        const f32x4 acc = c0 * p15 + c1 * q1 + c2 * q2 + c3 * q3;

        // wave writes 8 consecutive channels x 128 B = 1 KB contiguous
        __builtin_nontemporal_store(acc,
            reinterpret_cast<f32x4*>(out + ((size_t)bcur * IN_DIM + g) * OUT_DIM + sub * 4));

        xv = xn;
    }
}

extern "C" void kernel_launch(void* const* d_in, const int* in_sizes, int n_in,
                              void* d_out, int out_size, void* d_ws, size_t ws_size,
                              hipStream_t stream) {
    const float* X      = (const float*)d_in[0];
    const float* params = (const float*)d_in[1];
    float*       out    = (float*)d_out;

    const int nblocks = (IN_DIM / CH) * (BATCH / NB);   // 32 * 64 = 2048
    simplex_interp_lds<<<nblocks, 256, 0, stream>>>(X, params, out);
}

// Round 5
// 65.663 us; speedup vs baseline: 1.7663x; 1.2338x over previous
//
#include <hip/hip_runtime.h>

#define BATCH   4096
#define IN_DIM  512
#define OUT_DIM 32
#define CH      16   // channels per block
#define NB      64   // batches per block
#define NITER   32   // NB/2 : 256 threads = 2 batches x 16 ch x 8 subs

typedef float f32x4 __attribute__((ext_vector_type(4)));

__global__ __launch_bounds__(256) void simplex_interp_lds(
    const float* __restrict__ X,       // [BATCH, IN_DIM, 4]
    const float* __restrict__ params,  // [IN_DIM, 16, OUT_DIM]
    float* __restrict__ out)           // [BATCH, IN_DIM, OUT_DIM]
{
    __shared__ float lds_p[CH * 16 * OUT_DIM];  // 32 KB params tile
    __shared__ float lds_x[NB * CH * 4];        // 16 KB X tile

    const int tid = threadIdx.x;
    const int cg  = blockIdx.x & 31;           // channel group (512/CH = 32)
    const int bg  = blockIdx.x >> 5;           // batch group (0..63)
    const int b0  = bg * NB;
    const int g0  = cg * CH;

    // ---- stage params tile: 32 KB contiguous ----
    {
        const float* src = params + (size_t)cg * (CH * 16 * OUT_DIM);
        #pragma unroll
        for (int k = 0; k < 8; ++k) {
            const int off = (k * 256 + tid) * 4;
            *reinterpret_cast<f32x4*>(&lds_p[off]) =
                *reinterpret_cast<const f32x4*>(src + off);
        }
    }
    // ---- stage X tile: 64 batches x 16 ch x 16B = 16 KB (1024 f32x4, 4/thread)
    {
        #pragma unroll
        for (int k = 0; k < 4; ++k) {
            const int chunk = k * 256 + tid;        // 0..1023
            const int b     = chunk >> 4;           // local batch
            const int pos   = chunk & 15;           // f32x4 within the 256B row
            const size_t goff = ((size_t)(b0 + b) * IN_DIM + g0) * 4 + pos * 4;
            *reinterpret_cast<f32x4*>(&lds_x[b * (CH * 4) + pos * 4]) =
                __builtin_nontemporal_load(reinterpret_cast<const f32x4*>(X + goff));
        }
    }
    __syncthreads();

    const int half = tid >> 7;          // which of the 2 batches per iteration
    const int c    = (tid >> 3) & 15;   // local channel
    const int sub  = tid & 7;           // float4 slice of the 32 outputs
    const int g    = g0 + c;

    const float* ldsc = &lds_p[c * (16 * OUT_DIM) + sub * 4];
    const f32x4  p15  = *reinterpret_cast<const f32x4*>(ldsc + 15 * OUT_DIM);

    #pragma unroll 4
    for (int i = 0; i < NITER; ++i) {
        const int lb = 2 * i + half;    // local batch index
        const f32x4 xv = *reinterpret_cast<const f32x4*>(&lds_x[lb * (CH * 4) + c * 4]);

        // ---- 5-comparator sort network, ascending (branchless) ----
        float v0 = xv.x, v1 = xv.y, v2 = xv.z, v3 = xv.w;
        int   i0 = 0,    i1 = 1,    i2 = 2,    i3 = 3;
#define CSWAP(va, vb, ia, ib)                                            \
        {                                                                \
            bool lt = (vb) < (va);                                       \
            float tv = (va); (va) = lt ? (vb) : (va); (vb) = lt ? tv : (vb); \
            int   ti = (ia); (ia) = lt ? (ib) : (ia); (ib) = lt ? ti : (ib); \
        }
        CSWAP(v0, v1, i0, i1)
        CSWAP(v2, v3, i2, i3)
        CSWAP(v0, v2, i0, i2)
        CSWAP(v1, v3, i1, i3)
        CSWAP(v1, v2, i1, i2)
#undef CSWAP

        const float c0 = v0;
        const float c1 = v1 - v0;
        const float c2 = v2 - v1;
        const float c3 = v3 - v2;

        const int idx3 = (1 << i3);
        const int idx2 = idx3 + (1 << i2);
        const int idx1 = idx2 + (1 << i1);

        // ---- LDS gathers: each 8-lane group reads a full 128-B row ----
        const f32x4 q1 = *reinterpret_cast<const f32x4*>(ldsc + idx1 * OUT_DIM);
        const f32x4 q2 = *reinterpret_cast<const f32x4*>(ldsc + idx2 * OUT_DIM);
        const f32x4 q3 = *reinterpret_cast<const f32x4*>(ldsc + idx3 * OUT_DIM);

        const f32x4 acc = c0 * p15 + c1 * q1 + c2 * q2 + c3 * q3;

        // fire-and-forget streaming store (never awaited inside the loop)
        __builtin_nontemporal_store(acc,
            reinterpret_cast<f32x4*>(out + ((size_t)(b0 + lb) * IN_DIM + g) * OUT_DIM + sub * 4));
    }
}

extern "C" void kernel_launch(void* const* d_in, const int* in_sizes, int n_in,
                              void* d_out, int out_size, void* d_ws, size_t ws_size,
                              hipStream_t stream) {
    const float* X      = (const float*)d_in[0];
    const float* params = (const float*)d_in[1];
    float*       out    = (float*)d_out;

    const int nblocks = (IN_DIM / CH) * (BATCH / NB);   // 32 * 64 = 2048
    simplex_interp_lds<<<nblocks, 256, 0, stream>>>(X, params, out);
}

// Round 6
// 54.349 us; speedup vs baseline: 2.1339x; 1.2082x over previous
//
#include <hip/hip_runtime.h>

#define BATCH   4096
#define IN_DIM  512
#define OUT_DIM 32
#define CH      8     // channels per block
#define NB      64    // batches per X group
#define NGROUP  4     // X groups per block
#define CGRID   (IN_DIM / CH)            // 64
#define BGRID   (BATCH / (NB * NGROUP))  // 16

typedef float f32x4 __attribute__((ext_vector_type(4)));

__global__ __launch_bounds__(256) void simplex_interp_persist(
    const float* __restrict__ X,       // [BATCH, IN_DIM, 4]
    const float* __restrict__ params,  // [IN_DIM, 16, OUT_DIM]
    float* __restrict__ out)           // [BATCH, IN_DIM, OUT_DIM]
{
    __shared__ float lds_p[CH * 16 * OUT_DIM];   // 16 KB params tile
    __shared__ float lds_x[NB * CH * 4];         // 8 KB X tile (single buffer)

    const int tid = threadIdx.x;
    const int cg  = blockIdx.x & (CGRID - 1);
    const int bg  = blockIdx.x >> 6;             // / CGRID
    const int g0  = cg * CH;
    const int b0  = bg * (NB * NGROUP);

    // ---- stage params tile: 16 KB contiguous, ONCE per block ----
    {
        const float* src = params + (size_t)g0 * (16 * OUT_DIM);
        #pragma unroll
        for (int k = 0; k < 4; ++k) {
            const int off = (k * 256 + tid) * 4;
            *reinterpret_cast<f32x4*>(&lds_p[off]) =
                *reinterpret_cast<const f32x4*>(src + off);
        }
    }

    // X group staging helpers (register path, so loads can be issued early)
    const int xchunk0 = tid;          // chunk ids: tid, tid+256
    const int xlb0    = xchunk0 >> 3;
    const int xpos0   = xchunk0 & 7;
    const int xchunk1 = 256 + tid;
    const int xlb1    = xchunk1 >> 3;
    const int xpos1   = xchunk1 & 7;

    f32x4 ra, rb;
    auto load_x = [&](int grp) {
        const size_t base = ((size_t)(b0 + grp * NB) * IN_DIM + g0) * 4;
        ra = __builtin_nontemporal_load(
            reinterpret_cast<const f32x4*>(X + base + (size_t)xlb0 * (IN_DIM * 4) + xpos0 * 4));
        rb = __builtin_nontemporal_load(
            reinterpret_cast<const f32x4*>(X + base + (size_t)xlb1 * (IN_DIM * 4) + xpos1 * 4));
    };
    auto write_x = [&]() {
        *reinterpret_cast<f32x4*>(&lds_x[xlb0 * (CH * 4) + xpos0 * 4]) = ra;
        *reinterpret_cast<f32x4*>(&lds_x[xlb1 * (CH * 4) + xpos1 * 4]) = rb;
    };

    load_x(0);
    write_x();
    __syncthreads();

    const int bq  = tid >> 6;          // wave id: which batch this iteration
    const int c   = (tid >> 3) & 7;    // local channel
    const int sub = tid & 7;           // float4 slice of the 32 outputs
    const int g   = g0 + c;

    const float* ldsc = &lds_p[c * (16 * OUT_DIM) + sub * 4];
    const f32x4  p15  = *reinterpret_cast<const f32x4*>(ldsc + 15 * OUT_DIM);

    for (int grp = 0; grp < NGROUP; ++grp) {
        // prefetch next group's X: loads issue now, land during the 16 iters
        if (grp + 1 < NGROUP) load_x(grp + 1);

        const int bbase = b0 + grp * NB;
        #pragma unroll 4
        for (int i = 0; i < NB / 4; ++i) {
            const int lb = i * 4 + bq;
            const f32x4 xv = *reinterpret_cast<const f32x4*>(&lds_x[lb * (CH * 4) + c * 4]);

            // ---- 5-comparator sort network, ascending (branchless) ----
            float v0 = xv.x, v1 = xv.y, v2 = xv.z, v3 = xv.w;
            int   i0 = 0,    i1 = 1,    i2 = 2,    i3 = 3;
#define CSWAP(va, vb, ia, ib)                                            \
            {                                                            \
                bool lt = (vb) < (va);                                   \
                float tv = (va); (va) = lt ? (vb) : (va); (vb) = lt ? tv : (vb); \
                int   ti = (ia); (ia) = lt ? (ib) : (ia); (ib) = lt ? ti : (ib); \
            }
            CSWAP(v0, v1, i0, i1)
            CSWAP(v2, v3, i2, i3)
            CSWAP(v0, v2, i0, i2)
            CSWAP(v1, v3, i1, i3)
            CSWAP(v1, v2, i1, i2)
#undef CSWAP

            const float c0 = v0;
            const float c1 = v1 - v0;
            const float c2 = v2 - v1;
            const float c3 = v3 - v2;

            const int idx3 = (1 << i3);
            const int idx2 = idx3 + (1 << i2);
            const int idx1 = idx2 + (1 << i1);

            // LDS gathers: each 8-lane group reads one full 128-B row
            const f32x4 q1 = *reinterpret_cast<const f32x4*>(ldsc + idx1 * OUT_DIM);
            const f32x4 q2 = *reinterpret_cast<const f32x4*>(ldsc + idx2 * OUT_DIM);
            const f32x4 q3 = *reinterpret_cast<const f32x4*>(ldsc + idx3 * OUT_DIM);

            const f32x4 acc = c0 * p15 + c1 * q1 + c2 * q2 + c3 * q3;

            // plain store: through-L2 write path (fill-proven 6.9 TB/s)
            *reinterpret_cast<f32x4*>(
                out + ((size_t)(bbase + lb) * IN_DIM + g) * OUT_DIM + sub * 4) = acc;
        }

        __syncthreads();                       // all reads of lds_x done
        if (grp + 1 < NGROUP) write_x();       // staged regs -> LDS
        __syncthreads();                       // writes visible
    }
}

extern "C" void kernel_launch(void* const* d_in, const int* in_sizes, int n_in,
                              void* d_out, int out_size, void* d_ws, size_t ws_size,
                              hipStream_t stream) {
    const float* X      = (const float*)d_in[0];
    const float* params = (const float*)d_in[1];
    float*       out    = (float*)d_out;

    const int nblocks = CGRID * BGRID;   // 64 * 16 = 1024
    simplex_interp_persist<<<nblocks, 256, 0, stream>>>(X, params, out);
}